// Round 1
// baseline (70.846 us; speedup 1.0000x reference)
//
#include <hip/hip_runtime.h>
#include <math.h>

#define PI_F 3.14159265358979323846f

// QuantumProjection — R11: FUSED single kernel.
// Evidence: per-iteration poison fill writes 512 MB (rocprof: fillBufferAligned,
// WRITE_SIZE=524288 KB @ ~7.1 TB/s) -> L3 (256 MB) is fully evicted each iter, so x is
// NOT L3-resident for K1. Both halves are pure HBM streams (read 134 MB / write 134 MB).
// Split serialized the two directions (~40 us ideal) + bubble + 2 ramps = 50.5 us measured.
// Fused: 268 MB mixed at ~6.3 TB/s copy-BW ~= 42.6 us, one launch, angles stay in regs.
// Components kept verbatim from the proven split kernels:
//   - K1 structure: one wave = 4 samples, lane covers x[{4L..4L+3} u {256+4L..+3}],
//     17-shfl fold -> lane l holds angle(sample=(l>>2)&3, wire=l&3) for ALL lanes
//     (xor16/xor32 folds duplicate lanes mod 16).
//   - K2 structure: 16-lane group simulates one sample's 16-amp state redundantly;
//     out GEMM = 2 coalesced NONTEMPORAL float4 stores per lane per row.
// R7 lesson: never cap launch_bounds below the register working set (spill -> 3x HBM).
// R9 lesson: NT *loads* of x regressed. R10: NT stores for out only (write-once).

typedef float floatx4 __attribute__((ext_vector_type(4)));

static __device__ __forceinline__ void nt_store4(float* p, floatx4 v)
{
    __builtin_nontemporal_store(v, reinterpret_cast<floatx4*>(p));
}

static __device__ __forceinline__ float fast_tanh(float a)
{
    a = fminf(fmaxf(a, -15.f), 15.f);
    const float e = __expf(2.f * a);
    return (e - 1.f) / (e + 1.f);
}

// wire w lives at bit (3-w) of the 16-amp index
template<int WIRE>
__device__ __forceinline__ void apply1q(float* sr, float* si,
    float u00r, float u00i, float u01r, float u01i,
    float u10r, float u10i, float u11r, float u11i)
{
    constexpr int st = 1 << (3 - WIRE);
#pragma unroll
    for (int i = 0; i < 16; ++i) {
        if (i & st) continue;
        const int j = i | st;
        const float r0 = sr[i], m0 = si[i], r1 = sr[j], m1 = si[j];
        sr[i] = u00r * r0 - u00i * m0 + u01r * r1 - u01i * m1;
        si[i] = u00r * m0 + u00i * r0 + u01r * m1 + u01i * r1;
        sr[j] = u10r * r0 - u10i * m0 + u11r * r1 - u11i * m1;
        si[j] = u10r * m0 + u10i * r0 + u11r * m1 + u11i * r1;
    }
}

template<int CW, int TW>
__device__ __forceinline__ void cnot(float* sr, float* si)
{
    constexpr int cb = 1 << (3 - CW), tb = 1 << (3 - TW);
#pragma unroll
    for (int i = 0; i < 16; ++i) {
        if ((i & cb) && !(i & tb)) {
            const int j = i | tb;
            float t;
            t = sr[i]; sr[i] = sr[j]; sr[j] = t;
            t = si[i]; si[i] = si[j]; si[j] = t;
        }
    }
}

// Wave-uniform gate via v_sin/v_cos (args in (-pi, 2pi): no range reduction needed)
#define APPLY_FAST(L, W) { \
    const float ph = wts[((L) * 4 + (W)) * 3 + 0]; \
    const float th = wts[((L) * 4 + (W)) * 3 + 1]; \
    const float om = wts[((L) * 4 + (W)) * 3 + 2]; \
    const float s_  = __sinf(0.5f * th),        c_  = __cosf(0.5f * th); \
    const float sp_ = __sinf(0.5f * (ph + om)), cp_ = __cosf(0.5f * (ph + om)); \
    const float sq_ = __sinf(0.5f * (ph - om)), cq_ = __cosf(0.5f * (ph - om)); \
    apply1q<W>(sr, si, cp_ * c_, -sp_ * c_, -cq_ * s_, -sq_ * s_, \
                       cq_ * s_, -sq_ * s_, cp_ * c_,  sp_ * c_); }

// One wave = 4 samples end-to-end: dot -> fold -> circuit (16 lanes/sample) -> out GEMM.
__global__ __launch_bounds__(256) void k_fused(
    const float* __restrict__ x,
    const float* __restrict__ preW,
    const float* __restrict__ preb,
    const float* __restrict__ wts,
    const float* __restrict__ postW,
    const float* __restrict__ postb,
    float* __restrict__ out, int B)
{
    const int lane = threadIdx.x & 63;
    const int wv   = (blockIdx.x * blockDim.x + threadIdx.x) >> 6;
    const int b0   = wv * 4;
    if (b0 >= B) return;

    // ---------- Phase 1: angles (K1 structure, verbatim) ----------
    // Issue the HBM x loads FIRST (long latency), then the L2-hot weight loads.
    float4 xa[4], xb[4];
#pragma unroll
    for (int t = 0; t < 4; ++t) {
        const float* xr = x + (size_t)(b0 + t) * 512;
        xa[t] = *reinterpret_cast<const float4*>(xr + lane * 4);
        xb[t] = *reinterpret_cast<const float4*>(xr + 256 + lane * 4);
    }
    float4 wA[4], wB[4];
#pragma unroll
    for (int w = 0; w < 4; ++w) {
        wA[w] = *reinterpret_cast<const float4*>(preW + w * 512 + lane * 4);
        wB[w] = *reinterpret_cast<const float4*>(preW + w * 512 + 256 + lane * 4);
    }
    const float4 pb = *reinterpret_cast<const float4*>(preb);

    float acc[4][4];
#pragma unroll
    for (int t = 0; t < 4; ++t) {
#pragma unroll
        for (int w = 0; w < 4; ++w) {
            acc[t][w] = xa[t].x * wA[w].x + xa[t].y * wA[w].y + xa[t].z * wA[w].z + xa[t].w * wA[w].w
                      + xb[t].x * wB[w].x + xb[t].y * wB[w].y + xb[t].z * wB[w].z + xb[t].w * wB[w].w;
        }
    }

    // 17-shfl fold: after xor16/xor32 every lane l holds the full dot for
    // sample (l>>2)&3, wire l&3 (lanes >=16 are duplicates of lanes 0..15).
    float v[4];
#pragma unroll
    for (int t = 0; t < 4; ++t) {
        float a01 = (lane & 1) ? acc[t][1] : acc[t][0];
        float b01 = (lane & 1) ? acc[t][0] : acc[t][1];
        a01 += __shfl_xor(b01, 1, 64);
        float a23 = (lane & 1) ? acc[t][3] : acc[t][2];
        float b23 = (lane & 1) ? acc[t][2] : acc[t][3];
        a23 += __shfl_xor(b23, 1, 64);
        const float vv = (lane & 2) ? a23 : a01;
        const float uu = (lane & 2) ? a01 : a23;
        v[t] = vv + __shfl_xor(uu, 2, 64);
    }
    float c01 = (lane & 4) ? v[1] : v[0];
    float d01 = (lane & 4) ? v[0] : v[1];
    c01 += __shfl_xor(d01, 4, 64);
    float c23 = (lane & 4) ? v[3] : v[2];
    float d23 = (lane & 4) ? v[2] : v[3];
    c23 += __shfl_xor(d23, 4, 64);
    float m = (lane & 8) ? c23 : c01;
    float n = (lane & 8) ? c01 : c23;
    m += __shfl_xor(n, 8, 64);
    m += __shfl_xor(m, 16, 64);
    m += __shfl_xor(m, 32, 64);

    const float pb01 = (lane & 1) ? pb.y : pb.x;
    const float pb23 = (lane & 1) ? pb.w : pb.z;
    const float pbv  = (lane & 2) ? pb23 : pb01;
    const float angv = fast_tanh(m + pbv) * PI_F;   // valid on ALL lanes

    // ---------- Phase 2: circuit (K2 structure) ----------
    // 16-lane group simulates sample t16 = lane>>4; fetch its 4 angles via shfl
    // (source lanes 4*t16+w are < 16, where the fold results are canonical).
    const int t16 = lane >> 4;
    const float a0 = __shfl(angv, t16 * 4 + 0, 64);
    const float a1 = __shfl(angv, t16 * 4 + 1, 64);
    const float a2 = __shfl(angv, t16 * 4 + 2, 64);
    const float a3 = __shfl(angv, t16 * 4 + 3, 64);

    // RX embedding: amp[i] = prod_w (c_w or -i s_w); a/2 in (-pi/2,pi/2)
    const float s0 = __sinf(0.5f * a0), c0 = __cosf(0.5f * a0);
    const float s1 = __sinf(0.5f * a1), c1 = __cosf(0.5f * a1);
    const float s2 = __sinf(0.5f * a2), c2 = __cosf(0.5f * a2);
    const float s3 = __sinf(0.5f * a3), c3 = __cosf(0.5f * a3);

    float sr[16], si[16];
#pragma unroll
    for (int i = 0; i < 16; ++i) {
        const float r = ((i & 8) ? s0 : c0) * ((i & 4) ? s1 : c1)
                      * ((i & 2) ? s2 : c2) * ((i & 1) ? s3 : c3);
        const int mm = (((i >> 3) & 1) + ((i >> 2) & 1) + ((i >> 1) & 1) + (i & 1)) & 3;
        switch (mm) {                // multiply by (-i)^popcount
            case 0:  sr[i] = r;    si[i] = 0.f; break;
            case 1:  sr[i] = 0.f;  si[i] = -r;  break;
            case 2:  sr[i] = -r;   si[i] = 0.f; break;
            default: sr[i] = 0.f;  si[i] = r;   break;
        }
    }

    APPLY_FAST(0, 0); APPLY_FAST(0, 1); APPLY_FAST(0, 2); APPLY_FAST(0, 3);
    cnot<0, 1>(sr, si); cnot<1, 2>(sr, si); cnot<2, 3>(sr, si); cnot<3, 0>(sr, si);
    APPLY_FAST(1, 0); APPLY_FAST(1, 1); APPLY_FAST(1, 2); APPLY_FAST(1, 3);
    cnot<0, 2>(sr, si); cnot<1, 3>(sr, si); cnot<2, 0>(sr, si); cnot<3, 1>(sr, si);

    float z0 = 0.f, z1 = 0.f, z2 = 0.f, z3 = 0.f;
#pragma unroll
    for (int i = 0; i < 16; ++i) {
        const float p = sr[i] * sr[i] + si[i] * si[i];
        z0 += (i & 8) ? -p : p;
        z1 += (i & 4) ? -p : p;
        z2 += (i & 2) ? -p : p;
        z3 += (i & 1) ? -p : p;
    }

    // ---------- Phase 3: out GEMM (K2 store pattern, 4 rows) ----------
    const float4* pW4 = reinterpret_cast<const float4*>(postW);   // row o = postW[o][:]
    const float4* pb4 = reinterpret_cast<const float4*>(postb);
    const float4 p0 = pW4[4 * lane + 0], p1 = pW4[4 * lane + 1];
    const float4 p2 = pW4[4 * lane + 2], p3 = pW4[4 * lane + 3];
    const float4 p4 = pW4[4 * (64 + lane) + 0], p5 = pW4[4 * (64 + lane) + 1];
    const float4 p6 = pW4[4 * (64 + lane) + 2], p7 = pW4[4 * (64 + lane) + 3];
    const float4 bb0 = pb4[lane], bb1 = pb4[64 + lane];

#pragma unroll
    for (int s = 0; s < 4; ++s) {
        // sample s's z values live (identically) in lanes [16s .. 16s+15]
        const float q0 = __shfl(z0, s * 16, 64);
        const float q1 = __shfl(z1, s * 16, 64);
        const float q2 = __shfl(z2, s * 16, 64);
        const float q3 = __shfl(z3, s * 16, 64);
        floatx4 o0, o1;
        o0.x = fmaf(q3, p0.w, fmaf(q2, p0.z, fmaf(q1, p0.y, fmaf(q0, p0.x, bb0.x))));
        o0.y = fmaf(q3, p1.w, fmaf(q2, p1.z, fmaf(q1, p1.y, fmaf(q0, p1.x, bb0.y))));
        o0.z = fmaf(q3, p2.w, fmaf(q2, p2.z, fmaf(q1, p2.y, fmaf(q0, p2.x, bb0.z))));
        o0.w = fmaf(q3, p3.w, fmaf(q2, p3.z, fmaf(q1, p3.y, fmaf(q0, p3.x, bb0.w))));
        o1.x = fmaf(q3, p4.w, fmaf(q2, p4.z, fmaf(q1, p4.y, fmaf(q0, p4.x, bb1.x))));
        o1.y = fmaf(q3, p5.w, fmaf(q2, p5.z, fmaf(q1, p5.y, fmaf(q0, p5.x, bb1.y))));
        o1.z = fmaf(q3, p6.w, fmaf(q2, p6.z, fmaf(q1, p6.y, fmaf(q0, p6.x, bb1.z))));
        o1.w = fmaf(q3, p7.w, fmaf(q2, p7.z, fmaf(q1, p7.y, fmaf(q0, p7.x, bb1.w))));
        float* orow = out + (size_t)(b0 + s) * 512;
        nt_store4(orow + 4 * lane, o0);          // cols [lane*4, +4)
        nt_store4(orow + 256 + 4 * lane, o1);    // cols [256+lane*4, +4)
    }
}

extern "C" void kernel_launch(void* const* d_in, const int* in_sizes, int n_in,
                              void* d_out, int out_size, void* d_ws, size_t ws_size,
                              hipStream_t stream)
{
    const float* x     = (const float*)d_in[0];
    const float* preW  = (const float*)d_in[1];
    const float* preb  = (const float*)d_in[2];
    const float* wts   = (const float*)d_in[3];
    const float* postW = (const float*)d_in[4];
    const float* postb = (const float*)d_in[5];
    float* out = (float*)d_out;
    const int B = in_sizes[0] / 512;

    // 4 waves/block, 4 samples/wave -> 16 samples/block
    k_fused<<<dim3((B + 15) / 16), dim3(256), 0, stream>>>(
        x, preW, preb, wts, postW, postb, out, B);
}

// Round 2
// 49.990 us; speedup vs baseline: 1.4172x; 1.4172x over previous
//
#include <hip/hip_runtime.h>
#include <math.h>

#define PI_F 3.14159265358979323846f

// QuantumProjection — R12: fused single kernel, LDS angle hand-off.
// R11 post-mortem: fusing with 4 samples/wave end-to-end made the circuit phase
// 4x redundant per sample (16 lanes/sample vs K2's 4 lanes/sample) -> VALU-bound
// (VALUBusy 68%, HBM 31%, 80us). Fix: block = 64 samples; phase 1 = K1 dot wave
// (4 samples/pass x 4 passes), angles -> 1KB LDS; __syncthreads; phase 2+3 = K2
// verbatim (one wave = 16 samples, 4 lanes/sample circuit + NT-store out GEMM).
// Per-sample VALU back to split-kernel levels; fusion keeps one launch, no bubble,
// no angle round-trip, concurrent read+write streams.
// Evidence kept from earlier rounds:
//  - R7: never cap launch_bounds below register working set (spill -> 3x HBM).
//  - R9: NT loads of x forfeit L3 half-residency (R11 FETCH=66MB of 134MB confirms
//    L3 retains ~half of x even across the 512MB poison fill) -> plain loads.
//  - R10: NT stores for out only (write-once stream).

typedef float floatx4 __attribute__((ext_vector_type(4)));

static __device__ __forceinline__ void nt_store4(float* p, floatx4 v)
{
    __builtin_nontemporal_store(v, reinterpret_cast<floatx4*>(p));
}

static __device__ __forceinline__ float fast_tanh(float a)
{
    a = fminf(fmaxf(a, -15.f), 15.f);
    const float e = __expf(2.f * a);
    return (e - 1.f) / (e + 1.f);
}

// wire w lives at bit (3-w) of the 16-amp index
template<int WIRE>
__device__ __forceinline__ void apply1q(float* sr, float* si,
    float u00r, float u00i, float u01r, float u01i,
    float u10r, float u10i, float u11r, float u11i)
{
    constexpr int st = 1 << (3 - WIRE);
#pragma unroll
    for (int i = 0; i < 16; ++i) {
        if (i & st) continue;
        const int j = i | st;
        const float r0 = sr[i], m0 = si[i], r1 = sr[j], m1 = si[j];
        sr[i] = u00r * r0 - u00i * m0 + u01r * r1 - u01i * m1;
        si[i] = u00r * m0 + u00i * r0 + u01r * m1 + u01i * r1;
        sr[j] = u10r * r0 - u10i * m0 + u11r * r1 - u11i * m1;
        si[j] = u10r * m0 + u10i * r0 + u11r * m1 + u11i * r1;
    }
}

template<int CW, int TW>
__device__ __forceinline__ void cnot(float* sr, float* si)
{
    constexpr int cb = 1 << (3 - CW), tb = 1 << (3 - TW);
#pragma unroll
    for (int i = 0; i < 16; ++i) {
        if ((i & cb) && !(i & tb)) {
            const int j = i | tb;
            float t;
            t = sr[i]; sr[i] = sr[j]; sr[j] = t;
            t = si[i]; si[i] = si[j]; si[j] = t;
        }
    }
}

// Wave-uniform gate via v_sin/v_cos (args in (-pi, 2pi): no range reduction needed)
#define APPLY_FAST(L, W) { \
    const float ph = wts[((L) * 4 + (W)) * 3 + 0]; \
    const float th = wts[((L) * 4 + (W)) * 3 + 1]; \
    const float om = wts[((L) * 4 + (W)) * 3 + 2]; \
    const float s_  = __sinf(0.5f * th),        c_  = __cosf(0.5f * th); \
    const float sp_ = __sinf(0.5f * (ph + om)), cp_ = __cosf(0.5f * (ph + om)); \
    const float sq_ = __sinf(0.5f * (ph - om)), cq_ = __cosf(0.5f * (ph - om)); \
    apply1q<W>(sr, si, cp_ * c_, -sp_ * c_, -cq_ * s_, -sq_ * s_, \
                       cq_ * s_, -sq_ * s_, cp_ * c_,  sp_ * c_); }

// Block = 256 threads = 4 waves = 64 samples.
// Phase 1 (per wave, 4 passes of 4 samples): K1 dot + 17-shfl fold -> angles in LDS.
// Phase 2+3 (per wave, 16 samples): K2 circuit (4 lanes/sample) + NT-store out GEMM.
__global__ __launch_bounds__(256) void k_fused(
    const float* __restrict__ x,
    const float* __restrict__ preW,
    const float* __restrict__ preb,
    const float* __restrict__ wts,
    const float* __restrict__ postW,
    const float* __restrict__ postb,
    float* __restrict__ out, int B)
{
    const int lane  = threadIdx.x & 63;
    const int wid   = threadIdx.x >> 6;          // wave in block, 0..3
    const int base  = blockIdx.x * 64;           // 64 samples per block
    const int wbase = base + wid * 16;           // this wave's 16 samples
    if (base >= B) return;

    __shared__ float4 angLds[64];                // [sampleLocal] -> 4 angles

    // ---------- Phase 1: angles (K1 structure, 4 passes) ----------
    float4 wA[4], wB[4];
#pragma unroll
    for (int w = 0; w < 4; ++w) {
        wA[w] = *reinterpret_cast<const float4*>(preW + w * 512 + lane * 4);
        wB[w] = *reinterpret_cast<const float4*>(preW + w * 512 + 256 + lane * 4);
    }
    const float4 pb = *reinterpret_cast<const float4*>(preb);

#pragma unroll
    for (int p = 0; p < 4; ++p) {
        const int b0 = wbase + p * 4;

        float4 xa[4], xb[4];
#pragma unroll
        for (int t = 0; t < 4; ++t) {
            const float* xr = x + (size_t)(b0 + t) * 512;
            xa[t] = *reinterpret_cast<const float4*>(xr + lane * 4);
            xb[t] = *reinterpret_cast<const float4*>(xr + 256 + lane * 4);
        }

        float acc[4][4];
#pragma unroll
        for (int t = 0; t < 4; ++t) {
#pragma unroll
            for (int w = 0; w < 4; ++w) {
                acc[t][w] = xa[t].x * wA[w].x + xa[t].y * wA[w].y + xa[t].z * wA[w].z + xa[t].w * wA[w].w
                          + xb[t].x * wB[w].x + xb[t].y * wB[w].y + xb[t].z * wB[w].z + xb[t].w * wB[w].w;
            }
        }

        // 17-shfl fold: lane l (<16) ends with dot for sample (l>>2), wire l&3
        float v[4];
#pragma unroll
        for (int t = 0; t < 4; ++t) {
            float a01 = (lane & 1) ? acc[t][1] : acc[t][0];
            float b01 = (lane & 1) ? acc[t][0] : acc[t][1];
            a01 += __shfl_xor(b01, 1, 64);
            float a23 = (lane & 1) ? acc[t][3] : acc[t][2];
            float b23 = (lane & 1) ? acc[t][2] : acc[t][3];
            a23 += __shfl_xor(b23, 1, 64);
            const float vv = (lane & 2) ? a23 : a01;
            const float uu = (lane & 2) ? a01 : a23;
            v[t] = vv + __shfl_xor(uu, 2, 64);
        }
        float c01 = (lane & 4) ? v[1] : v[0];
        float d01 = (lane & 4) ? v[0] : v[1];
        c01 += __shfl_xor(d01, 4, 64);
        float c23 = (lane & 4) ? v[3] : v[2];
        float d23 = (lane & 4) ? v[2] : v[3];
        c23 += __shfl_xor(d23, 4, 64);
        float m = (lane & 8) ? c23 : c01;
        float n = (lane & 8) ? c01 : c23;
        m += __shfl_xor(n, 8, 64);
        m += __shfl_xor(m, 16, 64);
        m += __shfl_xor(m, 32, 64);

        const float pb01 = (lane & 1) ? pb.y : pb.x;
        const float pb23 = (lane & 1) ? pb.w : pb.z;
        const float pbv  = (lane & 2) ? pb23 : pb01;
        const float angv = fast_tanh(m + pbv) * PI_F;

        if (lane < 16) {
            float* arow = reinterpret_cast<float*>(&angLds[wid * 16 + p * 4 + (lane >> 2)]);
            arow[lane & 3] = angv;               // 16 consecutive floats: conflict-free
        }
    }

    __syncthreads();

    // ---------- Phase 2: circuit (K2 structure verbatim, 16 samples/wave) ----------
    const int sid = lane >> 2;                   // 0..15
    const float4 ang = angLds[wid * 16 + sid];   // 16B rows, 2-way bank alias = free

    // RX embedding: amp[i] = prod_w (c_w or -i s_w); a/2 in (-pi/2,pi/2)
    const float s0 = __sinf(0.5f * ang.x), c0 = __cosf(0.5f * ang.x);
    const float s1 = __sinf(0.5f * ang.y), c1 = __cosf(0.5f * ang.y);
    const float s2 = __sinf(0.5f * ang.z), c2 = __cosf(0.5f * ang.z);
    const float s3 = __sinf(0.5f * ang.w), c3 = __cosf(0.5f * ang.w);

    float sr[16], si[16];
#pragma unroll
    for (int i = 0; i < 16; ++i) {
        const float r = ((i & 8) ? s0 : c0) * ((i & 4) ? s1 : c1)
                      * ((i & 2) ? s2 : c2) * ((i & 1) ? s3 : c3);
        const int mm = (((i >> 3) & 1) + ((i >> 2) & 1) + ((i >> 1) & 1) + (i & 1)) & 3;
        switch (mm) {                // multiply by (-i)^popcount
            case 0:  sr[i] = r;    si[i] = 0.f; break;
            case 1:  sr[i] = 0.f;  si[i] = -r;  break;
            case 2:  sr[i] = -r;   si[i] = 0.f; break;
            default: sr[i] = 0.f;  si[i] = r;   break;
        }
    }

    APPLY_FAST(0, 0); APPLY_FAST(0, 1); APPLY_FAST(0, 2); APPLY_FAST(0, 3);
    cnot<0, 1>(sr, si); cnot<1, 2>(sr, si); cnot<2, 3>(sr, si); cnot<3, 0>(sr, si);
    APPLY_FAST(1, 0); APPLY_FAST(1, 1); APPLY_FAST(1, 2); APPLY_FAST(1, 3);
    cnot<0, 2>(sr, si); cnot<1, 3>(sr, si); cnot<2, 0>(sr, si); cnot<3, 1>(sr, si);

    float z0 = 0.f, z1 = 0.f, z2 = 0.f, z3 = 0.f;
#pragma unroll
    for (int i = 0; i < 16; ++i) {
        const float p = sr[i] * sr[i] + si[i] * si[i];
        z0 += (i & 8) ? -p : p;
        z1 += (i & 4) ? -p : p;
        z2 += (i & 2) ? -p : p;
        z3 += (i & 1) ? -p : p;
    }

    // ---------- Phase 3: out GEMM (K2 store pattern verbatim, 16 rows/wave) ----------
    const float4* pW4 = reinterpret_cast<const float4*>(postW);   // row o = postW[o][:]
    const float4* pb4 = reinterpret_cast<const float4*>(postb);
    const float4 p0 = pW4[4 * lane + 0], p1 = pW4[4 * lane + 1];
    const float4 p2 = pW4[4 * lane + 2], p3 = pW4[4 * lane + 3];
    const float4 p4 = pW4[4 * (64 + lane) + 0], p5 = pW4[4 * (64 + lane) + 1];
    const float4 p6 = pW4[4 * (64 + lane) + 2], p7 = pW4[4 * (64 + lane) + 3];
    const float4 bb0 = pb4[lane], bb1 = pb4[64 + lane];

#pragma unroll
    for (int s = 0; s < 16; ++s) {
        // sample s's z values live (identically) in lanes [4s .. 4s+3]
        const float q0 = __shfl(z0, s * 4, 64);
        const float q1 = __shfl(z1, s * 4, 64);
        const float q2 = __shfl(z2, s * 4, 64);
        const float q3 = __shfl(z3, s * 4, 64);
        floatx4 o0, o1;
        o0.x = fmaf(q3, p0.w, fmaf(q2, p0.z, fmaf(q1, p0.y, fmaf(q0, p0.x, bb0.x))));
        o0.y = fmaf(q3, p1.w, fmaf(q2, p1.z, fmaf(q1, p1.y, fmaf(q0, p1.x, bb0.y))));
        o0.z = fmaf(q3, p2.w, fmaf(q2, p2.z, fmaf(q1, p2.y, fmaf(q0, p2.x, bb0.z))));
        o0.w = fmaf(q3, p3.w, fmaf(q2, p3.z, fmaf(q1, p3.y, fmaf(q0, p3.x, bb0.w))));
        o1.x = fmaf(q3, p4.w, fmaf(q2, p4.z, fmaf(q1, p4.y, fmaf(q0, p4.x, bb1.x))));
        o1.y = fmaf(q3, p5.w, fmaf(q2, p5.z, fmaf(q1, p5.y, fmaf(q0, p5.x, bb1.y))));
        o1.z = fmaf(q3, p6.w, fmaf(q2, p6.z, fmaf(q1, p6.y, fmaf(q0, p6.x, bb1.z))));
        o1.w = fmaf(q3, p7.w, fmaf(q2, p7.z, fmaf(q1, p7.y, fmaf(q0, p7.x, bb1.w))));
        float* orow = out + (size_t)(wbase + s) * 512;
        nt_store4(orow + 4 * lane, o0);          // cols [lane*4, +4)
        nt_store4(orow + 256 + 4 * lane, o1);    // cols [256+lane*4, +4)
    }
}

extern "C" void kernel_launch(void* const* d_in, const int* in_sizes, int n_in,
                              void* d_out, int out_size, void* d_ws, size_t ws_size,
                              hipStream_t stream)
{
    const float* x     = (const float*)d_in[0];
    const float* preW  = (const float*)d_in[1];
    const float* preb  = (const float*)d_in[2];
    const float* wts   = (const float*)d_in[3];
    const float* postW = (const float*)d_in[4];
    const float* postb = (const float*)d_in[5];
    float* out = (float*)d_out;
    const int B = in_sizes[0] / 512;

    // 4 waves/block, 64 samples/block
    k_fused<<<dim3((B + 63) / 64), dim3(256), 0, stream>>>(
        x, preW, preb, wts, postW, postb, out, B);
}